// Round 4
// baseline (832.644 us; speedup 1.0000x reference)
//
#include <hip/hip_runtime.h>
#include <math.h>

#define N_NODES 256
#define T_DIM   30000
#define H_DIM   512
#define L_DIM   256
#define NB      256    // chain blocks (one per CU; co-resident for barrier)

// ---------------- P = I + C ----------------
__global__ void k_init_P(float* P, unsigned* sync, float* u) {
    int t = blockIdx.x * blockDim.x + threadIdx.x; // 65536 threads
    P[t] = ((t >> 8) == (t & 255)) ? 1.0f : 0.0f;
    if (t < 8) sync[t] = 0u;   // cnt, gen, dem(float), pad
    if (t < 256) u[t] = 0.0f;
}

__global__ void k_count_edges(const int* __restrict__ idx, int E, float* P) {
    int e = blockIdx.x * blockDim.x + threadIdx.x;
    if (e < E) {
        int s = idx[e];
        int d = idx[E + e];
        atomicAdd(&P[d * N_NODES + s], 1.0f);
    }
}

__global__ void k_zero(float* p, int n) {
    int t = blockIdx.x * blockDim.x + threadIdx.x;
    if (t < n) p[t] = 0.0f;
}

// ---------------- big GEMM: Y1 = x @ Ws1a ----------------
// x [256,30000] row-major, W [30000,512] row-major.
// grid (4,2,nz): 128x128 tile, K split; kc = K elems per z-slice.
template<bool ATOMIC>
__global__ __launch_bounds__(256)
void k_gemm_big(const float* __restrict__ x, const float* __restrict__ W,
                float* __restrict__ outp, int kc) {
    __shared__ float xs[16 * 140];
    __shared__ float ws[16 * 132];

    const int t  = threadIdx.x;
    const int bx = blockIdx.x;
    const int by = blockIdx.y;
    const int z  = blockIdx.z;
    const int rowBase = by * 128;
    const int colBase = bx * 128;
    const int kb0  = z * kc;
    const int kend = min(kb0 + kc, T_DIM);
    const int nchunk = (kend > kb0) ? ((kend - kb0) >> 4) : 0;

    const int lr  = t >> 2;
    const int lkq = (t & 3) * 4;
    const int wkk = t >> 5;
    const int wcq = (t & 31) * 4;
    const int tx  = t & 15, ty = t >> 4;

    float acc[8][8];
    #pragma unroll
    for (int i = 0; i < 8; ++i)
        #pragma unroll
        for (int j = 0; j < 8; ++j) acc[i][j] = 0.0f;

    if (nchunk > 0) {
        float4 xa, xb, wa, wb;
        {
            const float* xp = x + (size_t)(rowBase + lr) * T_DIM + kb0 + lkq;
            xa = *(const float4*)xp;
            xb = *(const float4*)(xp + (size_t)64 * T_DIM);
            const float* wp = W + (size_t)(kb0 + wkk) * H_DIM + colBase + wcq;
            wa = *(const float4*)wp;
            wb = *(const float4*)(wp + 8 * H_DIM);
        }

        for (int c = 0; c < nchunk; ++c) {
            __syncthreads();
            xs[(lkq + 0) * 140 + lr] = xa.x;
            xs[(lkq + 1) * 140 + lr] = xa.y;
            xs[(lkq + 2) * 140 + lr] = xa.z;
            xs[(lkq + 3) * 140 + lr] = xa.w;
            xs[(lkq + 0) * 140 + lr + 64] = xb.x;
            xs[(lkq + 1) * 140 + lr + 64] = xb.y;
            xs[(lkq + 2) * 140 + lr + 64] = xb.z;
            xs[(lkq + 3) * 140 + lr + 64] = xb.w;
            *(float4*)&ws[wkk * 132 + wcq]       = wa;
            *(float4*)&ws[(wkk + 8) * 132 + wcq] = wb;
            __syncthreads();

            if (c + 1 < nchunk) {
                int kb = kb0 + (c + 1) * 16;
                const float* xp = x + (size_t)(rowBase + lr) * T_DIM + kb + lkq;
                xa = *(const float4*)xp;
                xb = *(const float4*)(xp + (size_t)64 * T_DIM);
                const float* wp = W + (size_t)(kb + wkk) * H_DIM + colBase + wcq;
                wa = *(const float4*)wp;
                wb = *(const float4*)(wp + 8 * H_DIM);
            }

            #pragma unroll
            for (int kk = 0; kk < 16; ++kk) {
                float a[8], b[8];
                *(float4*)&a[0] = *(const float4*)&xs[kk * 140 + ty * 8];
                *(float4*)&a[4] = *(const float4*)&xs[kk * 140 + ty * 8 + 4];
                *(float4*)&b[0] = *(const float4*)&ws[kk * 132 + tx * 8];
                *(float4*)&b[4] = *(const float4*)&ws[kk * 132 + tx * 8 + 4];
                #pragma unroll
                for (int i = 0; i < 8; ++i)
                    #pragma unroll
                    for (int j = 0; j < 8; ++j)
                        acc[i][j] = fmaf(a[i], b[j], acc[i][j]);
            }
        }
    }

    if (ATOMIC) {
        if (nchunk == 0) return;
        #pragma unroll
        for (int i = 0; i < 8; ++i) {
            int r = rowBase + ty * 8 + i;
            #pragma unroll
            for (int j = 0; j < 8; ++j)
                atomicAdd(&outp[r * H_DIM + colBase + tx * 8 + j], acc[i][j]);
        }
    } else {
        float* op = outp + (size_t)z * (N_NODES * H_DIM);
        #pragma unroll
        for (int i = 0; i < 8; ++i) {
            int r = rowBase + ty * 8 + i;
            *(float4*)&op[r * H_DIM + colBase + tx * 8]     = *(float4*)&acc[i][0];
            *(float4*)&op[r * H_DIM + colBase + tx * 8 + 4] = *(float4*)&acc[i][4];
        }
    }
}

// ---------------- fused chain ----------------
struct ChainArgs {
    const float* P;
    const float* Y1p;
    float* Y1;
    float* bufA;
    float* bufB;
    float* feat;
    float* u;
    unsigned* cnt; unsigned* gen; float* dem;
    const float* bs1a;
    const float* Ws1b; const float* bs1b;
    const float* Ws2a; const float* bs2a;
    const float* Ws2b; const float* bs2b;
    const float* Wc1a; const float* bc1a;
    const float* Wc1b; const float* bc1b;
    const float* Wc2a; const float* bc2a;
    const float* Wc2b; const float* bc2b;
    const float* Wd;   const float* bd;
    float* out;
    int nz;
};

__device__ __forceinline__ void gbar(unsigned* cnt, unsigned* gen, unsigned nb) {
    __threadfence();
    __syncthreads();
    if (threadIdx.x == 0) {
        unsigned g = __hip_atomic_load(gen, __ATOMIC_RELAXED, __HIP_MEMORY_SCOPE_AGENT);
        unsigned arrived = __hip_atomic_fetch_add(cnt, 1u, __ATOMIC_ACQ_REL,
                                                  __HIP_MEMORY_SCOPE_AGENT);
        if (arrived == nb - 1u) {
            __hip_atomic_store(cnt, 0u, __ATOMIC_RELAXED, __HIP_MEMORY_SCOPE_AGENT);
            __hip_atomic_fetch_add(gen, 1u, __ATOMIC_RELEASE, __HIP_MEMORY_SCOPE_AGENT);
        } else {
            while (__hip_atomic_load(gen, __ATOMIC_ACQUIRE,
                                     __HIP_MEMORY_SCOPE_AGENT) == g) {
                __builtin_amdgcn_s_sleep(1);
            }
        }
    }
    __syncthreads();
    __threadfence();
}

__device__ __forceinline__ float block_reduce(float v, float* red) {
    #pragma unroll
    for (int off = 32; off; off >>= 1) v += __shfl_down(v, off, 64);
    __syncthreads();
    if ((threadIdx.x & 63) == 0) red[threadIdx.x >> 6] = v;
    __syncthreads();
    return red[0] + red[1] + red[2] + red[3];
}

__device__ __forceinline__ float sigmoidf(float x) {
    return 1.0f / (1.0f + expf(-x));
}

// out[256 x N] = act(A[256 x K] @ B[K x N] + bias); tile 16 rows x 32 cols,
// K-chunk 64. Modes: normal store; dem-fused (Wd,dem); u-fused (uW,u — no store).
__device__ __forceinline__ void stage(const float* __restrict__ A,
                                      const float* __restrict__ B,
                                      const float* __restrict__ bias,
                                      float* __restrict__ out,
                                      int K, int N, int act,
                                      const float* Wd, float* dem,
                                      const float* uW, float* u,
                                      float* As /*64x17 [k][r]*/,
                                      float* Bs /*64x36 [k][c]*/,
                                      float* red) {
    const int nct = N >> 5;
    const int ntiles = nct << 4;
    const int b = blockIdx.x;
    if (b >= ntiles) return;
    const int r0 = (b / nct) << 4;
    const int c0 = (b % nct) << 5;
    const int t  = threadIdx.x;

    const int ar = t >> 4;          // A-load row 0..15
    const int ak = (t & 15) << 2;   // A-load k offset 0..60
    const int bk = t >> 2;          // B-load k row 0..63
    const int bc = (t & 3) << 3;    // B-load col offset 0,8,16,24
    const int c  = t & 31;          // output col
    const int r2 = (t >> 5) << 1;   // output rows r2, r2+1

    float acc0 = 0.f, acc1 = 0.f;
    for (int kb = 0; kb < K; kb += 64) {
        __syncthreads();
        float4 av = *(const float4*)&A[(size_t)(r0 + ar) * K + kb + ak];
        As[(ak + 0) * 17 + ar] = av.x;
        As[(ak + 1) * 17 + ar] = av.y;
        As[(ak + 2) * 17 + ar] = av.z;
        As[(ak + 3) * 17 + ar] = av.w;
        const float* bp = &B[(size_t)(kb + bk) * N + c0 + bc];
        *(float4*)&Bs[bk * 36 + bc]     = *(const float4*)bp;
        *(float4*)&Bs[bk * 36 + bc + 4] = *(const float4*)(bp + 4);
        __syncthreads();
        #pragma unroll
        for (int kk = 0; kk < 64; ++kk) {
            float bv = Bs[kk * 36 + c];
            acc0 = fmaf(As[kk * 17 + r2],     bv, acc0);
            acc1 = fmaf(As[kk * 17 + r2 + 1], bv, acc1);
        }
    }
    const int rr0 = r0 + r2, rr1 = rr0 + 1;
    const int cc = c0 + c;
    float bb = bias ? bias[cc] : 0.f;
    float v0 = acc0 + bb, v1 = acc1 + bb;
    if (act) { v0 = fmaxf(v0, 0.f); v1 = fmaxf(v1, 0.f); }

    if (u) {
        // u[r] += sum_c v(r,c) * uW[cc]; reduce across 32-lane col groups
        float s0 = v0 * uW[cc], s1 = v1 * uW[cc];
        #pragma unroll
        for (int off = 16; off; off >>= 1) {
            s0 += __shfl_down(s0, off, 32);
            s1 += __shfl_down(s1, off, 32);
        }
        if ((t & 31) == 0) {
            atomicAdd(&u[rr0], s0);
            atomicAdd(&u[rr1], s1);
        }
        return;
    }
    out[(size_t)rr0 * N + cc] = v0;
    out[(size_t)rr1 * N + cc] = v1;
    if (dem) {
        float p = v0 * Wd[rr0 * 256 + cc] + v1 * Wd[rr1 * 256 + cc];
        float tot = block_reduce(p, red);
        if (t == 0) atomicAdd(dem, tot);
    }
}

__global__ __launch_bounds__(256)
void k_chain(ChainArgs a) {
    __shared__ float As[64 * 17];
    __shared__ float Bs[64 * 36];
    __shared__ float red[4];
    const int t = threadIdx.x;
    const int b = blockIdx.x;

    // S0: reduce split-K partials -> Y1 (65536 threads x float2)
    if (a.nz > 0) {
        int i = b * 256 + t;
        const float2* pp = (const float2*)a.Y1p;
        float2 s = pp[i];
        #pragma unroll 4
        for (int z = 1; z < a.nz; ++z) {
            float2 v = pp[(size_t)z * 65536 + i];
            s.x += v.x; s.y += v.y;
        }
        ((float2*)a.Y1)[i] = s;
    }
    gbar(a.cnt, a.gen, NB);                                                  // B1
    // S1: t1 = relu(P@Y1 + bs1a)            [256x512]
    stage(a.P, a.Y1, a.bs1a, a.bufA, 256, 512, 1, 0, 0, 0, 0, As, Bs, red);
    gbar(a.cnt, a.gen, NB);                                                  // B2
    // S2: h1 = relu(t1@Ws1b + bs1b)         [256x512]
    stage(a.bufA, a.Ws1b, a.bs1b, a.bufB, 512, 512, 1, 0, 0, 0, 0, As, Bs, red);
    gbar(a.cnt, a.gen, NB);                                                  // B3
    // S3: A2 = P@h1                          [256x512]
    stage(a.P, a.bufB, 0, a.bufA, 256, 512, 0, 0, 0, 0, 0, As, Bs, red);
    gbar(a.cnt, a.gen, NB);                                                  // B4
    // S4: t2 = relu(A2@Ws2a + bs2a)          [256x256]
    stage(a.bufA, a.Ws2a, a.bs2a, a.bufB, 512, 256, 1, 0, 0, 0, 0, As, Bs, red);
    gbar(a.cnt, a.gen, NB);                                                  // B5
    // S5: feat = t2@Ws2b + bs2b  (+ dementia partial dot)   [256x256]
    stage(a.bufB, a.Ws2b, a.bs2b, a.feat, 256, 256, 0, a.Wd, a.dem, 0, 0, As, Bs, red);
    gbar(a.cnt, a.gen, NB);                                                  // B6
    // S6: A3 = P@feat                        [256x256]
    stage(a.P, a.feat, 0, a.bufA, 256, 256, 0, 0, 0, 0, 0, As, Bs, red);
    gbar(a.cnt, a.gen, NB);                                                  // B7
    // S7: t3 = relu(A3@Wc1a + bc1a)          [256x512]
    stage(a.bufA, a.Wc1a, a.bc1a, a.bufB, 256, 512, 1, 0, 0, 0, 0, As, Bs, red);
    gbar(a.cnt, a.gen, NB);                                                  // B8
    // S8: s1 = relu(t3@Wc1b + bc1b); u = s1@Wc2a (fused, no s1 store)
    stage(a.bufB, a.Wc1b, a.bc1b, 0, 512, 512, 1, 0, 0, a.Wc2a, a.u, As, Bs, red);
    gbar(a.cnt, a.gen, NB);                                                  // B9

    // S10: v = P@u; scores; dementia head
    {
        float pv = a.P[b * 256 + t] * a.u[t];
        float v = block_reduce(pv, red);
        if (t == 0) {
            float h2 = fmaxf(v + a.bc2a[0], 0.f);
            a.out[1 + b] = sigmoidf(h2 * a.Wc2b[0] + a.bc2b[0]);
            if (b == 0) a.out[0] = sigmoidf(*a.dem + a.bd[0]);
        }
    }
}

extern "C" void kernel_launch(void* const* d_in, const int* in_sizes, int n_in,
                              void* d_out, int out_size, void* d_ws, size_t ws_size,
                              hipStream_t stream) {
    const float* x    = (const float*)d_in[0];
    const int*   idx  = (const int*)d_in[1];
    const float* Ws1a = (const float*)d_in[3];
    ChainArgs a;
    a.bs1a = (const float*)d_in[4];
    a.Ws1b = (const float*)d_in[5];  a.bs1b = (const float*)d_in[6];
    a.Ws2a = (const float*)d_in[7];  a.bs2a = (const float*)d_in[8];
    a.Ws2b = (const float*)d_in[9];  a.bs2b = (const float*)d_in[10];
    a.Wc1a = (const float*)d_in[11]; a.bc1a = (const float*)d_in[12];
    a.Wc1b = (const float*)d_in[13]; a.bc1b = (const float*)d_in[14];
    a.Wc2a = (const float*)d_in[15]; a.bc2a = (const float*)d_in[16];
    a.Wc2b = (const float*)d_in[17]; a.bc2b = (const float*)d_in[18];
    a.Wd   = (const float*)d_in[19]; a.bd   = (const float*)d_in[20];
    a.out  = (float*)d_out;
    const int E = in_sizes[1] / 2;

    float* w    = (float*)d_ws;
    float* P    = w;                  // 65536
    float* Y1   = P + 65536;          // 131072
    float* bufA = Y1 + 131072;        // 131072
    float* bufB = bufA + 131072;      // 131072
    float* feat = bufB + 131072;      // 65536
    float* u    = feat + 65536;       // 256
    float* syncf = u + 256;           // 64 (cnt, gen, dem, pad)
    float* Y1p  = syncf + 64;

    // how many split-K slices fit in the remaining workspace?
    const long long fixed = (long long)(Y1p - w);
    const long long avail = (long long)(ws_size / 4) - fixed;
    int maxsplit = (avail > 0) ? (int)(avail / 131072) : 0;
    int nz = 0, kc = 0;
    const int CH = 1875;  // 30000/16 k-chunks
    if (maxsplit >= 2) {
        int splits = maxsplit < 125 ? maxsplit : 125;
        int chunks = (CH + splits - 1) / splits;
        nz = (CH + chunks - 1) / chunks;
        kc = chunks * 16;
    }

    a.P = P; a.Y1 = Y1; a.Y1p = Y1p;
    a.bufA = bufA; a.bufB = bufB; a.feat = feat; a.u = u;
    a.cnt = (unsigned*)syncf; a.gen = ((unsigned*)syncf) + 1;
    a.dem = syncf + 2;
    a.nz = nz;

    // adjacency P = I + C; zero barrier state, dem, u
    k_init_P<<<256, 256, 0, stream>>>(P, (unsigned*)syncf, u);
    k_count_edges<<<(E + 255) / 256, 256, 0, stream>>>(idx, E, P);

    // Y1 = x @ Ws1a   (P@(x@W) == (P@x)@W)
    if (nz > 0) {
        k_gemm_big<false><<<dim3(4, 2, nz), 256, 0, stream>>>(x, Ws1a, Y1p, kc);
    } else {
        k_zero<<<512, 256, 0, stream>>>(Y1, N_NODES * H_DIM);
        k_gemm_big<true><<<dim3(4, 2, 63), 256, 0, stream>>>(x, Ws1a, Y1, 480);
    }

    // fused chain: 256 persistent blocks, distributed stages, 9 grid barriers
    k_chain<<<NB, 256, 0, stream>>>(a);
}

// Round 5
// 699.033 us; speedup vs baseline: 1.1911x; 1.1911x over previous
//
#include <hip/hip_runtime.h>
#include <math.h>

#define N_NODES 256
#define T_DIM   30000
#define H_DIM   512
#define L_DIM   256

// ---------------- P = I + C ----------------
__global__ void k_init_P(float* P, float* dem, float* u) {
    int t = blockIdx.x * blockDim.x + threadIdx.x; // 65536 threads
    P[t] = ((t >> 8) == (t & 255)) ? 1.0f : 0.0f;
    if (t == 0) *dem = 0.0f;
    if (t < 256) u[t] = 0.0f;
}

__global__ void k_count_edges(const int* __restrict__ idx, int E, float* P) {
    int e = blockIdx.x * blockDim.x + threadIdx.x;
    if (e < E) {
        int s = idx[e];
        int d = idx[E + e];
        atomicAdd(&P[d * N_NODES + s], 1.0f);
    }
}

__global__ void k_zero(float* p, int n) {
    int t = blockIdx.x * blockDim.x + threadIdx.x;
    if (t < n) p[t] = 0.0f;
}

// ---------------- big GEMM: Y1 = x @ Ws1a ----------------
// x [256,30000] rm, W [30000,512] rm. grid (4,2,nz): 128x128 tile, K split.
template<bool ATOMIC>
__global__ __launch_bounds__(256)
void k_gemm_big(const float* __restrict__ x, const float* __restrict__ W,
                float* __restrict__ outp, int kc) {
    __shared__ float xs[16 * 140];
    __shared__ float ws[16 * 132];

    const int t  = threadIdx.x;
    const int bx = blockIdx.x;
    const int by = blockIdx.y;
    const int z  = blockIdx.z;
    const int rowBase = by * 128;
    const int colBase = bx * 128;
    const int kb0  = z * kc;
    const int kend = min(kb0 + kc, T_DIM);
    const int nchunk = (kend > kb0) ? ((kend - kb0) >> 4) : 0;

    const int lr  = t >> 2;
    const int lkq = (t & 3) * 4;
    const int wkk = t >> 5;
    const int wcq = (t & 31) * 4;
    const int tx  = t & 15, ty = t >> 4;

    float acc[8][8];
    #pragma unroll
    for (int i = 0; i < 8; ++i)
        #pragma unroll
        for (int j = 0; j < 8; ++j) acc[i][j] = 0.0f;

    if (nchunk > 0) {
        float4 xa, xb, wa, wb;
        {
            const float* xp = x + (size_t)(rowBase + lr) * T_DIM + kb0 + lkq;
            xa = *(const float4*)xp;
            xb = *(const float4*)(xp + (size_t)64 * T_DIM);
            const float* wp = W + (size_t)(kb0 + wkk) * H_DIM + colBase + wcq;
            wa = *(const float4*)wp;
            wb = *(const float4*)(wp + 8 * H_DIM);
        }

        for (int c = 0; c < nchunk; ++c) {
            __syncthreads();
            xs[(lkq + 0) * 140 + lr] = xa.x;
            xs[(lkq + 1) * 140 + lr] = xa.y;
            xs[(lkq + 2) * 140 + lr] = xa.z;
            xs[(lkq + 3) * 140 + lr] = xa.w;
            xs[(lkq + 0) * 140 + lr + 64] = xb.x;
            xs[(lkq + 1) * 140 + lr + 64] = xb.y;
            xs[(lkq + 2) * 140 + lr + 64] = xb.z;
            xs[(lkq + 3) * 140 + lr + 64] = xb.w;
            *(float4*)&ws[wkk * 132 + wcq]       = wa;
            *(float4*)&ws[(wkk + 8) * 132 + wcq] = wb;
            __syncthreads();

            if (c + 1 < nchunk) {
                int kb = kb0 + (c + 1) * 16;
                const float* xp = x + (size_t)(rowBase + lr) * T_DIM + kb + lkq;
                xa = *(const float4*)xp;
                xb = *(const float4*)(xp + (size_t)64 * T_DIM);
                const float* wp = W + (size_t)(kb + wkk) * H_DIM + colBase + wcq;
                wa = *(const float4*)wp;
                wb = *(const float4*)(wp + 8 * H_DIM);
            }

            #pragma unroll
            for (int kk = 0; kk < 16; ++kk) {
                float a[8], b[8];
                *(float4*)&a[0] = *(const float4*)&xs[kk * 140 + ty * 8];
                *(float4*)&a[4] = *(const float4*)&xs[kk * 140 + ty * 8 + 4];
                *(float4*)&b[0] = *(const float4*)&ws[kk * 132 + tx * 8];
                *(float4*)&b[4] = *(const float4*)&ws[kk * 132 + tx * 8 + 4];
                #pragma unroll
                for (int i = 0; i < 8; ++i)
                    #pragma unroll
                    for (int j = 0; j < 8; ++j)
                        acc[i][j] = fmaf(a[i], b[j], acc[i][j]);
            }
        }
    }

    if (ATOMIC) {
        if (nchunk == 0) return;
        #pragma unroll
        for (int i = 0; i < 8; ++i) {
            int r = rowBase + ty * 8 + i;
            #pragma unroll
            for (int j = 0; j < 8; ++j)
                atomicAdd(&outp[r * H_DIM + colBase + tx * 8 + j], acc[i][j]);
        }
    } else {
        float* op = outp + (size_t)z * (N_NODES * H_DIM);
        #pragma unroll
        for (int i = 0; i < 8; ++i) {
            int r = rowBase + ty * 8 + i;
            *(float4*)&op[r * H_DIM + colBase + tx * 8]     = *(float4*)&acc[i][0];
            *(float4*)&op[r * H_DIM + colBase + tx * 8 + 4] = *(float4*)&acc[i][4];
        }
    }
}

// reduce split-K partials -> Y1 (32768 float4 threads)
__global__ void k_reduce(const float4* __restrict__ Y1p, float4* __restrict__ Y1,
                         int nz) {
    int i = blockIdx.x * blockDim.x + threadIdx.x;
    float4 s = Y1p[i];
    #pragma unroll 8
    for (int z = 1; z < nz; ++z) {
        float4 v = Y1p[(size_t)z * 32768 + i];
        s.x += v.x; s.y += v.y; s.z += v.z; s.w += v.w;
    }
    Y1[i] = s;
}

// ---------------- stage GEMM (one kernel per stage) ----------------
// out[256 x N] = act(A[256 x K] @ B[K x N] + bias)
// tile 16 rows x 32 cols, K-chunk 64, grid = (N/32)*16 blocks x 256 threads.
// MODE 0: store; MODE 1: store + dementia partial dot; MODE 2: u-fuse, no store.
template<int K, int N, int MODE>
__global__ __launch_bounds__(256)
void k_stage(const float* __restrict__ A, const float* __restrict__ B,
             const float* __restrict__ bias, float* __restrict__ out, int act,
             const float* __restrict__ Wd, float* __restrict__ dem,
             const float* __restrict__ uW, float* __restrict__ u) {
    __shared__ float As[64 * 17];
    __shared__ float Bs[64 * 36];
    __shared__ float red[4];
    const int nct = N >> 5;
    const int b = blockIdx.x;
    const int r0 = (b / nct) << 4;
    const int c0 = (b % nct) << 5;
    const int t  = threadIdx.x;

    const int ar = t >> 4;          // A-load row 0..15
    const int ak = (t & 15) << 2;   // A-load k offset 0..60
    const int bk = t >> 2;          // B-load k row 0..63
    const int bc = (t & 3) << 3;    // B-load col offset 0,8,16,24
    const int c  = t & 31;          // output col
    const int r2 = (t >> 5) << 1;   // output rows r2, r2+1

    float acc0 = 0.f, acc1 = 0.f;
    #pragma unroll
    for (int kb = 0; kb < K; kb += 64) {
        __syncthreads();
        float4 av = *(const float4*)&A[(size_t)(r0 + ar) * K + kb + ak];
        As[(ak + 0) * 17 + ar] = av.x;
        As[(ak + 1) * 17 + ar] = av.y;
        As[(ak + 2) * 17 + ar] = av.z;
        As[(ak + 3) * 17 + ar] = av.w;
        const float* bp = &B[(size_t)(kb + bk) * N + c0 + bc];
        *(float4*)&Bs[bk * 36 + bc]     = *(const float4*)bp;
        *(float4*)&Bs[bk * 36 + bc + 4] = *(const float4*)(bp + 4);
        __syncthreads();
        #pragma unroll
        for (int kk = 0; kk < 64; ++kk) {
            float bv = Bs[kk * 36 + c];
            acc0 = fmaf(As[kk * 17 + r2],     bv, acc0);
            acc1 = fmaf(As[kk * 17 + r2 + 1], bv, acc1);
        }
    }
    const int rr0 = r0 + r2, rr1 = rr0 + 1;
    const int cc = c0 + c;
    float bb = bias ? bias[cc] : 0.f;
    float v0 = acc0 + bb, v1 = acc1 + bb;
    if (act) { v0 = fmaxf(v0, 0.f); v1 = fmaxf(v1, 0.f); }

    if (MODE == 2) {
        // u[r] += sum_c v(r,c) * uW[cc]
        float s0 = v0 * uW[cc], s1 = v1 * uW[cc];
        #pragma unroll
        for (int off = 16; off; off >>= 1) {
            s0 += __shfl_down(s0, off, 32);
            s1 += __shfl_down(s1, off, 32);
        }
        if ((t & 31) == 0) {
            atomicAdd(&u[rr0], s0);
            atomicAdd(&u[rr1], s1);
        }
        return;
    }
    out[(size_t)rr0 * N + cc] = v0;
    out[(size_t)rr1 * N + cc] = v1;
    if (MODE == 1) {
        float p = v0 * Wd[rr0 * 256 + cc] + v1 * Wd[rr1 * 256 + cc];
        #pragma unroll
        for (int off = 32; off; off >>= 1) p += __shfl_down(p, off, 64);
        __syncthreads();
        if ((t & 63) == 0) red[t >> 6] = p;
        __syncthreads();
        if (t == 0) atomicAdd(dem, red[0] + red[1] + red[2] + red[3]);
    }
}

__device__ __forceinline__ float sigmoidf(float x) {
    return 1.0f / (1.0f + expf(-x));
}

// final: v = P@u per row -> region scores; block 0 also emits dementia pred
__global__ __launch_bounds__(256)
void k_final(const float* __restrict__ P, const float* __restrict__ u,
             const float* __restrict__ dem,
             const float* __restrict__ bc2a, const float* __restrict__ Wc2b,
             const float* __restrict__ bc2b, const float* __restrict__ bd,
             float* __restrict__ out) {
    __shared__ float red[4];
    const int b = blockIdx.x, t = threadIdx.x;
    float pv = P[b * 256 + t] * u[t];
    #pragma unroll
    for (int off = 32; off; off >>= 1) pv += __shfl_down(pv, off, 64);
    if ((t & 63) == 0) red[t >> 6] = pv;
    __syncthreads();
    if (t == 0) {
        float v = red[0] + red[1] + red[2] + red[3];
        float h2 = fmaxf(v + bc2a[0], 0.f);
        out[1 + b] = sigmoidf(h2 * Wc2b[0] + bc2b[0]);
        if (b == 0) out[0] = sigmoidf(*dem + bd[0]);
    }
}

extern "C" void kernel_launch(void* const* d_in, const int* in_sizes, int n_in,
                              void* d_out, int out_size, void* d_ws, size_t ws_size,
                              hipStream_t stream) {
    const float* x    = (const float*)d_in[0];
    const int*   idx  = (const int*)d_in[1];
    const float* Ws1a = (const float*)d_in[3];
    const float* bs1a = (const float*)d_in[4];
    const float* Ws1b = (const float*)d_in[5];
    const float* bs1b = (const float*)d_in[6];
    const float* Ws2a = (const float*)d_in[7];
    const float* bs2a = (const float*)d_in[8];
    const float* Ws2b = (const float*)d_in[9];
    const float* bs2b = (const float*)d_in[10];
    const float* Wc1a = (const float*)d_in[11];
    const float* bc1a = (const float*)d_in[12];
    const float* Wc1b = (const float*)d_in[13];
    const float* bc1b = (const float*)d_in[14];
    const float* Wc2a = (const float*)d_in[15];
    const float* bc2a = (const float*)d_in[16];
    const float* Wc2b = (const float*)d_in[17];
    const float* bc2b = (const float*)d_in[18];
    const float* Wd   = (const float*)d_in[19];
    const float* bd   = (const float*)d_in[20];
    float* out = (float*)d_out;
    const int E = in_sizes[1] / 2;

    float* w    = (float*)d_ws;
    float* P    = w;                  // 65536
    float* Y1   = P + 65536;          // 131072
    float* bufA = Y1 + 131072;        // 131072
    float* bufB = bufA + 131072;      // 131072
    float* feat = bufB + 131072;      // 65536
    float* u    = feat + 65536;       // 256
    float* dem  = u + 256;            // 64 (dem + pad)
    float* Y1p  = dem + 64;

    // split-K slices that fit in remaining workspace (target 64, R1-measured)
    const long long fixed = (long long)(Y1p - w);
    const long long avail = (long long)(ws_size / 4) - fixed;
    int maxsplit = (avail > 0) ? (int)(avail / 131072) : 0;
    int nz = 0, kc = 0;
    const int CH = 1875;  // 30000/16 k-chunks
    if (maxsplit >= 2) {
        int splits = maxsplit < 64 ? maxsplit : 64;
        int chunks = (CH + splits - 1) / splits;
        nz = (CH + chunks - 1) / chunks;
        kc = chunks * 16;
    }

    // P = I + C; zero dem, u
    k_init_P<<<256, 256, 0, stream>>>(P, dem, u);
    k_count_edges<<<(E + 255) / 256, 256, 0, stream>>>(idx, E, P);

    // Y1 = x @ Ws1a   (P@(x@W) == (P@x)@W)
    if (nz > 0) {
        k_gemm_big<false><<<dim3(4, 2, nz), 256, 0, stream>>>(x, Ws1a, Y1p, kc);
        k_reduce<<<128, 256, 0, stream>>>((const float4*)Y1p, (float4*)Y1, nz);
    } else {
        k_zero<<<512, 256, 0, stream>>>(Y1, N_NODES * H_DIM);
        k_gemm_big<true><<<dim3(4, 2, 63), 256, 0, stream>>>(x, Ws1a, Y1, 480);
    }

    // stage chain (stream order is the barrier; ~1-2us graph-node gaps)
    k_stage<256, 512, 0><<<256, 256, 0, stream>>>(P,    Y1,   bs1a, bufA, 1, 0, 0, 0, 0);
    k_stage<512, 512, 0><<<256, 256, 0, stream>>>(bufA, Ws1b, bs1b, bufB, 1, 0, 0, 0, 0);
    k_stage<256, 512, 0><<<256, 256, 0, stream>>>(P,    bufB, 0,    bufA, 0, 0, 0, 0, 0);
    k_stage<512, 256, 0><<<128, 256, 0, stream>>>(bufA, Ws2a, bs2a, bufB, 1, 0, 0, 0, 0);
    k_stage<256, 256, 1><<<128, 256, 0, stream>>>(bufB, Ws2b, bs2b, feat, 0, Wd, dem, 0, 0);
    k_stage<256, 256, 0><<<128, 256, 0, stream>>>(P,    feat, 0,    bufA, 0, 0, 0, 0, 0);
    k_stage<256, 512, 0><<<256, 256, 0, stream>>>(bufA, Wc1a, bc1a, bufB, 1, 0, 0, 0, 0);
    k_stage<512, 512, 2><<<256, 256, 0, stream>>>(bufB, Wc1b, bc1b, 0,    1, 0, 0, Wc2a, u);
    k_final<<<256, 256, 0, stream>>>(P, u, dem, bc2a, Wc2b, bc2b, bd, out);
}

// Round 6
// 399.079 us; speedup vs baseline: 2.0864x; 1.7516x over previous
//
#include <hip/hip_runtime.h>
#include <math.h>

#define N_NODES 256
#define T_DIM   30000
#define H_DIM   512
#define L_DIM   256

// ---------------- P = I + C ----------------
__global__ void k_init_P(float* P, float* dem, float* u) {
    int t = blockIdx.x * blockDim.x + threadIdx.x; // 65536 threads
    P[t] = ((t >> 8) == (t & 255)) ? 1.0f : 0.0f;
    if (t == 0) *dem = 0.0f;
    if (t < 256) u[t] = 0.0f;
}

__global__ void k_count_edges(const int* __restrict__ idx, int E, float* P) {
    int e = blockIdx.x * blockDim.x + threadIdx.x;
    if (e < E) {
        int s = idx[e];
        int d = idx[E + e];
        atomicAdd(&P[d * N_NODES + s], 1.0f);
    }
}

__global__ void k_zero(float* p, int n) {
    int t = blockIdx.x * blockDim.x + threadIdx.x;
    if (t < n) p[t] = 0.0f;
}

// ---------------- big GEMM: Y1 = x @ Ws1a ----------------
// x [256,30000] rm, W [30000,512] rm. grid (4,2,nz): 128x128 tile, K split.
template<bool ATOMIC>
__global__ __launch_bounds__(256)
void k_gemm_big(const float* __restrict__ x, const float* __restrict__ W,
                float* __restrict__ outp, int kc) {
    __shared__ float xs[16 * 140];
    __shared__ float ws[16 * 132];

    const int t  = threadIdx.x;
    const int bx = blockIdx.x;
    const int by = blockIdx.y;
    const int z  = blockIdx.z;
    const int rowBase = by * 128;
    const int colBase = bx * 128;
    const int kb0  = z * kc;
    const int kend = min(kb0 + kc, T_DIM);
    const int nchunk = (kend > kb0) ? ((kend - kb0) >> 4) : 0;

    const int lr  = t >> 2;
    const int lkq = (t & 3) * 4;
    const int wkk = t >> 5;
    const int wcq = (t & 31) * 4;
    const int tx  = t & 15, ty = t >> 4;

    float acc[8][8];
    #pragma unroll
    for (int i = 0; i < 8; ++i)
        #pragma unroll
        for (int j = 0; j < 8; ++j) acc[i][j] = 0.0f;

    if (nchunk > 0) {
        float4 xa, xb, wa, wb;
        {
            const float* xp = x + (size_t)(rowBase + lr) * T_DIM + kb0 + lkq;
            xa = *(const float4*)xp;
            xb = *(const float4*)(xp + (size_t)64 * T_DIM);
            const float* wp = W + (size_t)(kb0 + wkk) * H_DIM + colBase + wcq;
            wa = *(const float4*)wp;
            wb = *(const float4*)(wp + 8 * H_DIM);
        }

        for (int c = 0; c < nchunk; ++c) {
            __syncthreads();
            xs[(lkq + 0) * 140 + lr] = xa.x;
            xs[(lkq + 1) * 140 + lr] = xa.y;
            xs[(lkq + 2) * 140 + lr] = xa.z;
            xs[(lkq + 3) * 140 + lr] = xa.w;
            xs[(lkq + 0) * 140 + lr + 64] = xb.x;
            xs[(lkq + 1) * 140 + lr + 64] = xb.y;
            xs[(lkq + 2) * 140 + lr + 64] = xb.z;
            xs[(lkq + 3) * 140 + lr + 64] = xb.w;
            *(float4*)&ws[wkk * 132 + wcq]       = wa;
            *(float4*)&ws[(wkk + 8) * 132 + wcq] = wb;
            __syncthreads();

            if (c + 1 < nchunk) {
                int kb = kb0 + (c + 1) * 16;
                const float* xp = x + (size_t)(rowBase + lr) * T_DIM + kb + lkq;
                xa = *(const float4*)xp;
                xb = *(const float4*)(xp + (size_t)64 * T_DIM);
                const float* wp = W + (size_t)(kb + wkk) * H_DIM + colBase + wcq;
                wa = *(const float4*)wp;
                wb = *(const float4*)(wp + 8 * H_DIM);
            }

            #pragma unroll
            for (int kk = 0; kk < 16; ++kk) {
                float a[8], b[8];
                *(float4*)&a[0] = *(const float4*)&xs[kk * 140 + ty * 8];
                *(float4*)&a[4] = *(const float4*)&xs[kk * 140 + ty * 8 + 4];
                *(float4*)&b[0] = *(const float4*)&ws[kk * 132 + tx * 8];
                *(float4*)&b[4] = *(const float4*)&ws[kk * 132 + tx * 8 + 4];
                #pragma unroll
                for (int i = 0; i < 8; ++i)
                    #pragma unroll
                    for (int j = 0; j < 8; ++j)
                        acc[i][j] = fmaf(a[i], b[j], acc[i][j]);
            }
        }
    }

    if (ATOMIC) {
        if (nchunk == 0) return;
        #pragma unroll
        for (int i = 0; i < 8; ++i) {
            int r = rowBase + ty * 8 + i;
            #pragma unroll
            for (int j = 0; j < 8; ++j)
                atomicAdd(&outp[r * H_DIM + colBase + tx * 8 + j], acc[i][j]);
        }
    } else {
        float* op = outp + (size_t)z * (N_NODES * H_DIM);
        #pragma unroll
        for (int i = 0; i < 8; ++i) {
            int r = rowBase + ty * 8 + i;
            *(float4*)&op[r * H_DIM + colBase + tx * 8]     = *(float4*)&acc[i][0];
            *(float4*)&op[r * H_DIM + colBase + tx * 8 + 4] = *(float4*)&acc[i][4];
        }
    }
}

// reduce split-K partials -> Y1 (32768 float4 threads)
__global__ void k_reduce(const float4* __restrict__ Y1p, float4* __restrict__ Y1,
                         int nz) {
    int i = blockIdx.x * blockDim.x + threadIdx.x;
    float4 s = Y1p[i];
    for (int z = 1; z < nz; ++z) {
        float4 v = Y1p[(size_t)z * 32768 + i];
        s.x += v.x; s.y += v.y; s.z += v.z; s.w += v.w;
    }
    Y1[i] = s;
}

// ---------------- stage GEMM (one kernel per stage) ----------------
// out[256 x N] = act(A[256 x K] @ B[K x N] + bias)
// tile 16 rows x 32 cols, K-chunk 64, grid = (N/32)*16 blocks x 256 threads.
// MODE 0: store; MODE 1: store + dementia partial dot; MODE 2: u-fuse, no store.
template<int K, int N, int MODE>
__global__ __launch_bounds__(256)
void k_stage(const float* __restrict__ A, const float* __restrict__ B,
             const float* __restrict__ bias, float* __restrict__ out, int act,
             const float* __restrict__ Wd, float* __restrict__ dem,
             const float* __restrict__ uW, float* __restrict__ u) {
    __shared__ float As[64 * 17];
    __shared__ float Bs[64 * 36];
    __shared__ float red[4];
    const int nct = N >> 5;
    const int b = blockIdx.x;
    const int r0 = (b / nct) << 4;
    const int c0 = (b % nct) << 5;
    const int t  = threadIdx.x;

    const int ar = t >> 4;          // A-load row 0..15
    const int ak = (t & 15) << 2;   // A-load k offset 0..60
    const int bk = t >> 2;          // B-load k row 0..63
    const int bc = (t & 3) << 3;    // B-load col offset 0,8,16,24
    const int c  = t & 31;          // output col
    const int r2 = (t >> 5) << 1;   // output rows r2, r2+1

    float acc0 = 0.f, acc1 = 0.f;
    // NOTE: unroll 1 is load-bearing. R5 let this loop fully unroll
    // (compile-time K) -> VGPR 256 + ~4KB/thread scratch spill -> each
    // stage 198us of spill traffic (WRITE_SIZE 271MB). Keep it rolled.
    #pragma unroll 1
    for (int kb = 0; kb < K; kb += 64) {
        __syncthreads();
        float4 av = *(const float4*)&A[(size_t)(r0 + ar) * K + kb + ak];
        As[(ak + 0) * 17 + ar] = av.x;
        As[(ak + 1) * 17 + ar] = av.y;
        As[(ak + 2) * 17 + ar] = av.z;
        As[(ak + 3) * 17 + ar] = av.w;
        const float* bp = &B[(size_t)(kb + bk) * N + c0 + bc];
        *(float4*)&Bs[bk * 36 + bc]     = *(const float4*)bp;
        *(float4*)&Bs[bk * 36 + bc + 4] = *(const float4*)(bp + 4);
        __syncthreads();
        #pragma unroll
        for (int kk = 0; kk < 64; ++kk) {
            float bv = Bs[kk * 36 + c];
            acc0 = fmaf(As[kk * 17 + r2],     bv, acc0);
            acc1 = fmaf(As[kk * 17 + r2 + 1], bv, acc1);
        }
    }
    const int rr0 = r0 + r2, rr1 = rr0 + 1;
    const int cc = c0 + c;
    float bb = bias ? bias[cc] : 0.f;
    float v0 = acc0 + bb, v1 = acc1 + bb;
    if (act) { v0 = fmaxf(v0, 0.f); v1 = fmaxf(v1, 0.f); }

    if (MODE == 2) {
        // u[r] += sum_c v(r,c) * uW[cc]
        float s0 = v0 * uW[cc], s1 = v1 * uW[cc];
        #pragma unroll
        for (int off = 16; off; off >>= 1) {
            s0 += __shfl_down(s0, off, 32);
            s1 += __shfl_down(s1, off, 32);
        }
        if ((t & 31) == 0) {
            atomicAdd(&u[rr0], s0);
            atomicAdd(&u[rr1], s1);
        }
        return;
    }
    out[(size_t)rr0 * N + cc] = v0;
    out[(size_t)rr1 * N + cc] = v1;
    if (MODE == 1) {
        float p = v0 * Wd[rr0 * 256 + cc] + v1 * Wd[rr1 * 256 + cc];
        #pragma unroll
        for (int off = 32; off; off >>= 1) p += __shfl_down(p, off, 64);
        __syncthreads();
        if ((t & 63) == 0) red[t >> 6] = p;
        __syncthreads();
        if (t == 0) atomicAdd(dem, red[0] + red[1] + red[2] + red[3]);
    }
}

__device__ __forceinline__ float sigmoidf(float x) {
    return 1.0f / (1.0f + expf(-x));
}

// final: v = P@u per row -> region scores; block 0 also emits dementia pred
__global__ __launch_bounds__(256)
void k_final(const float* __restrict__ P, const float* __restrict__ u,
             const float* __restrict__ dem,
             const float* __restrict__ bc2a, const float* __restrict__ Wc2b,
             const float* __restrict__ bc2b, const float* __restrict__ bd,
             float* __restrict__ out) {
    __shared__ float red[4];
    const int b = blockIdx.x, t = threadIdx.x;
    float pv = P[b * 256 + t] * u[t];
    #pragma unroll
    for (int off = 32; off; off >>= 1) pv += __shfl_down(pv, off, 64);
    if ((t & 63) == 0) red[t >> 6] = pv;
    __syncthreads();
    if (t == 0) {
        float v = red[0] + red[1] + red[2] + red[3];
        float h2 = fmaxf(v + bc2a[0], 0.f);
        out[1 + b] = sigmoidf(h2 * Wc2b[0] + bc2b[0]);
        if (b == 0) out[0] = sigmoidf(*dem + bd[0]);
    }
}

extern "C" void kernel_launch(void* const* d_in, const int* in_sizes, int n_in,
                              void* d_out, int out_size, void* d_ws, size_t ws_size,
                              hipStream_t stream) {
    const float* x    = (const float*)d_in[0];
    const int*   idx  = (const int*)d_in[1];
    const float* Ws1a = (const float*)d_in[3];
    const float* bs1a = (const float*)d_in[4];
    const float* Ws1b = (const float*)d_in[5];
    const float* bs1b = (const float*)d_in[6];
    const float* Ws2a = (const float*)d_in[7];
    const float* bs2a = (const float*)d_in[8];
    const float* Ws2b = (const float*)d_in[9];
    const float* bs2b = (const float*)d_in[10];
    const float* Wc1a = (const float*)d_in[11];
    const float* bc1a = (const float*)d_in[12];
    const float* Wc1b = (const float*)d_in[13];
    const float* bc1b = (const float*)d_in[14];
    const float* Wc2a = (const float*)d_in[15];
    const float* bc2a = (const float*)d_in[16];
    const float* Wc2b = (const float*)d_in[17];
    const float* bc2b = (const float*)d_in[18];
    const float* Wd   = (const float*)d_in[19];
    const float* bd   = (const float*)d_in[20];
    float* out = (float*)d_out;
    const int E = in_sizes[1] / 2;

    float* w    = (float*)d_ws;
    float* P    = w;                  // 65536
    float* Y1   = P + 65536;          // 131072
    float* bufA = Y1 + 131072;        // 131072
    float* bufB = bufA + 131072;      // 131072
    float* feat = bufB + 131072;      // 65536
    float* u    = feat + 65536;       // 256
    float* dem  = u + 256;            // 64 (dem + pad)
    float* Y1p  = dem + 64;

    // split-K slices that fit in remaining workspace
    const long long fixed = (long long)(Y1p - w);
    const long long avail = (long long)(ws_size / 4) - fixed;
    int maxsplit = (avail > 0) ? (int)(avail / 131072) : 0;
    int nz = 0, kc = 0;
    const int CH = 1875;  // 30000/16 k-chunks
    if (maxsplit >= 2) {
        int splits = maxsplit < 64 ? maxsplit : 64;
        int chunks = (CH + splits - 1) / splits;
        nz = (CH + chunks - 1) / chunks;
        kc = chunks * 16;
    }

    // P = I + C; zero dem, u
    k_init_P<<<256, 256, 0, stream>>>(P, dem, u);
    k_count_edges<<<(E + 255) / 256, 256, 0, stream>>>(idx, E, P);

    // Y1 = x @ Ws1a   (P@(x@W) == (P@x)@W)
    if (nz > 0) {
        k_gemm_big<false><<<dim3(4, 2, nz), 256, 0, stream>>>(x, Ws1a, Y1p, kc);
        k_reduce<<<128, 256, 0, stream>>>((const float4*)Y1p, (float4*)Y1, nz);
    } else {
        k_zero<<<512, 256, 0, stream>>>(Y1, N_NODES * H_DIM);
        k_gemm_big<true><<<dim3(4, 2, 63), 256, 0, stream>>>(x, Ws1a, Y1, 480);
    }

    // stage chain (stream order is the barrier)
    k_stage<256, 512, 0><<<256, 256, 0, stream>>>(P,    Y1,   bs1a, bufA, 1, 0, 0, 0, 0);
    k_stage<512, 512, 0><<<256, 256, 0, stream>>>(bufA, Ws1b, bs1b, bufB, 1, 0, 0, 0, 0);
    k_stage<256, 512, 0><<<256, 256, 0, stream>>>(P,    bufB, 0,    bufA, 0, 0, 0, 0, 0);
    k_stage<512, 256, 0><<<128, 256, 0, stream>>>(bufA, Ws2a, bs2a, bufB, 1, 0, 0, 0, 0);
    k_stage<256, 256, 1><<<128, 256, 0, stream>>>(bufB, Ws2b, bs2b, feat, 0, Wd, dem, 0, 0);
    k_stage<256, 256, 0><<<128, 256, 0, stream>>>(P,    feat, 0,    bufA, 0, 0, 0, 0, 0);
    k_stage<256, 512, 0><<<256, 256, 0, stream>>>(bufA, Wc1a, bc1a, bufB, 1, 0, 0, 0, 0);
    k_stage<512, 512, 2><<<256, 256, 0, stream>>>(bufB, Wc1b, bc1b, 0,    1, 0, 0, Wc2a, u);
    k_final<<<256, 256, 0, stream>>>(P, u, dem, bc2a, Wc2b, bc2b, bd, out);
}